// Round 5
// baseline (190.833 us; speedup 1.0000x reference)
//
#include <hip/hip_runtime.h>
#include <hip/hip_bf16.h>

typedef __bf16 bf16_t;
typedef __bf16 bf16x2_t __attribute__((ext_vector_type(2)));
typedef __bf16 bf16x4_t __attribute__((ext_vector_type(4)));
typedef __bf16 bf16x8 __attribute__((ext_vector_type(8)));
typedef float f32x4 __attribute__((ext_vector_type(4)));
typedef float f32x16 __attribute__((ext_vector_type(16)));
typedef unsigned int u32x2 __attribute__((ext_vector_type(2)));

#define T_SEQ 1024
#define BATCH 8
#define NH 8
#define DH 128
#define HKDIM 1024  // NH*DH

static __device__ __forceinline__ f32x4 mfma16(bf16x8 a, bf16x8 b, f32x4 c) {
    return __builtin_amdgcn_mfma_f32_16x16x32_bf16(a, b, c, 0, 0, 0);
}
static __device__ __forceinline__ f32x16 mfma32(bf16x8 a, bf16x8 b, f32x16 c) {
    return __builtin_amdgcn_mfma_f32_32x32x16_bf16(a, b, c, 0, 0, 0);
}

static __device__ __forceinline__ unsigned pk2(float a, float b) {
    bf16x2_t t;
    t[0] = (bf16_t)a;
    t[1] = (bf16_t)b;
    union { bf16x2_t v; unsigned u; } c;
    c.v = t;
    return c.u;
}

// v_permlane32_swap via builtin: r[0] = {a.lo, b.lo}, r[1] = {a.hi, b.hi}
static __device__ __forceinline__ void plswap(unsigned& a, unsigned& b) {
    u32x2 r = __builtin_amdgcn_permlane32_swap(a, b, false, false);
    a = r[0];
    b = r[1];
}

// value of x from lane^32 (pure VALU, no DS)
static __device__ __forceinline__ float swap_partner(float x) {
    u32x2 r = __builtin_amdgcn_permlane32_swap(__float_as_uint(x),
                                               __float_as_uint(x), false, false);
    return __uint_as_float((threadIdx.x & 32) ? r[0] : r[1]);
}

// ---------------------------------------------------------------------------
// Kernel 1: convert inputs to bf16 working layouts (float4-vectorized).
// ---------------------------------------------------------------------------
__global__ __launch_bounds__(256) void convert_kernel(
        const float* __restrict__ x,
        const float* __restrict__ Wk, const float* __restrict__ Wq,
        const float* __restrict__ Wv, const float* __restrict__ Wo,
        bf16_t* __restrict__ xb, bf16_t* __restrict__ w3,
        bf16_t* __restrict__ wo) {
    const int n1 = T_SEQ * BATCH * DH;        // 1048576
    const int n2 = n1 + 3 * HKDIM * DH;       // +393216
    const int n3 = n2 + DH * HKDIM;           // +131072
    const int i = (blockIdx.x * 256 + threadIdx.x) * 4;
    if (i >= n3) return;
    const float* src;
    bf16_t* dst;
    if (i < n1) {
        int d = i & 127, t = (i >> 7) & 1023, b = i >> 17;
        src = x + (t * BATCH + b) * DH + d;
        dst = xb + i;
    } else if (i < n2) {
        int j = i - n1;
        int p = j >> 17;
        const float* W = (p == 0) ? Wk : (p == 1 ? Wq : Wv);
        src = W + (j & 131071);
        dst = w3 + j;
    } else {
        int j = i - n2;
        src = Wo + j;
        dst = wo + j;
    }
    f32x4 v = *(const f32x4*)src;
    bf16x4_t o;
    o[0] = (bf16_t)v[0]; o[1] = (bf16_t)v[1];
    o[2] = (bf16_t)v[2]; o[3] = (bf16_t)v[3];
    *(bf16x4_t*)dst = o;
}

// ---------------------------------------------------------------------------
// Kernel 2: QKV projection. K/Q written [bh][t][d]; V written TRANSPOSED
//   [bh][d][t] (feeds attention's PV A-fragments directly).
// ---------------------------------------------------------------------------
__global__ __launch_bounds__(256) void proj_kernel(
        const bf16_t* __restrict__ xb, const bf16_t* __restrict__ w3,
        const float* __restrict__ bk, const float* __restrict__ bq,
        const float* __restrict__ bv,
        bf16_t* __restrict__ kbuf, bf16_t* __restrict__ qbuf,
        bf16_t* __restrict__ vtbuf) {
    const int lane = threadIdx.x & 63;
    const int wave = threadIdx.x >> 6;
    const int lr = lane & 15, lq = lane >> 4;
    const int rm0 = blockIdx.x * 64 + wave * 16;
    const int cb0 = blockIdx.y * 64;

    bf16x8 aF[4];
#pragma unroll
    for (int kc = 0; kc < 4; ++kc)
        aF[kc] = *(const bf16x8*)(xb + (rm0 + lr) * DH + kc * 32 + lq * 8);

#pragma unroll
    for (int nc = 0; nc < 4; ++nc) {
        const int col0 = cb0 + nc * 16;
        f32x4 acc = {0.f, 0.f, 0.f, 0.f};
#pragma unroll
        for (int kc = 0; kc < 4; ++kc) {
            bf16x8 bF = *(const bf16x8*)(w3 + (col0 + lr) * DH + kc * 32 + lq * 8);
            acc = mfma16(aF[kc], bF, acc);
        }
        const int col = col0 + lr;
        const int p = col >> 10, within = col & 1023;
        const int h = within >> 7, d = within & 127;
        const float bias = (p == 0) ? bk[within] : (p == 1 ? bq[within] : bv[within]);
        if (p == 2) {
            // V transposed: vtbuf[bh][d][t]
#pragma unroll
            for (int r = 0; r < 4; ++r) {
                const int row = rm0 + lq * 4 + r;
                const int bb = row >> 10, tt = row & 1023;
                vtbuf[((size_t)(bb * NH + h) * DH + d) * T_SEQ + tt] =
                    (bf16_t)(acc[r] + bias);
            }
        } else {
            bf16_t* dst = (p == 0) ? kbuf : qbuf;
#pragma unroll
            for (int r = 0; r < 4; ++r) {
                const int row = rm0 + lq * 4 + r;
                const int bb = row >> 10, tt = row & 1023;
                dst[((size_t)(bb * NH + h) * T_SEQ + tt) * DH + d] =
                    (bf16_t)(acc[r] + bias);
            }
        }
    }
}

// ---------------------------------------------------------------------------
// Kernel 3: flash attention, 32x32 MFMA, in-lane softmax, permlane P-shuffle.
//   Roles: Q' := K_proj (rows i), K' := Q_proj (cols j), V := V_proj.
//   Block = 256 thr = 4 waves; wave w handles j-chunks w, w+4, w+8, ...
//   (max 8 chunks/wave -> tight intra-block balance). 4-way partial merge
//   via two 16KB LDS buffers at the end. Zero DS in the main loop.
//   Grid: 2048; bx>>6 = reversed itile (heavy first), bx&63 = bh.
// ---------------------------------------------------------------------------
__global__ __launch_bounds__(256) void attn_kernel(
        const bf16_t* __restrict__ kbuf, const bf16_t* __restrict__ qbuf,
        const bf16_t* __restrict__ vtb, bf16_t* __restrict__ obuf) {
    const int bx = blockIdx.x;
    const int itile = 31 - (bx >> 6);
    const int bh = bx & 63;
    const int b = bh >> 3, h = bh & 7;
    const int jseg = threadIdx.x >> 6;   // 0..3
    const int lane = threadIdx.x & 63;
    const int li = lane & 31;
    const int hi = lane >> 5;
    const int i0 = itile * 32;

    const bf16_t* Qp = kbuf + (size_t)bh * T_SEQ * DH;  // rows i (key positions)
    const bf16_t* Kp = qbuf + (size_t)bh * T_SEQ * DH;  // cols j (query positions)
    const bf16_t* Vt = vtb + (size_t)bh * DH * T_SEQ;   // [d][t]

    __shared__ float oLa[128][32];
    __shared__ float oLb[128][32];
    __shared__ float mlL[2][2][32];   // [buf][m/l][i]

    // persistent Q B-fragments: B[k=d][n=i], lane: i=li, k = s*16 + hi*8 + e
    bf16x8 qf[8];
#pragma unroll
    for (int s = 0; s < 8; ++s)
        qf[s] = *(const bf16x8*)(Qp + (size_t)(i0 + li) * DH + s * 16 + hi * 8);

    f32x16 oacc[4];
#pragma unroll
    for (int c = 0; c < 4; ++c)
#pragma unroll
        for (int e = 0; e < 16; ++e) oacc[c][e] = 0.f;

    float m = 0.f, l = 0.f;
    const float C = 0.08838834764831845f * 1.4426950408889634f;  // scale*log2e

    int jc = jseg;
    const bf16_t* kptr = Kp + (size_t)(jc * 32 + li) * DH + hi * 8;
    const bf16_t* vp0 = Vt + (size_t)li * T_SEQ + jc * 32 + hi * 8;
    const bf16_t* vp1 = vp0 + (size_t)32 * T_SEQ;
    const bf16_t* vp2 = vp0 + (size_t)64 * T_SEQ;
    const bf16_t* vp3 = vp0 + (size_t)96 * T_SEQ;

    // K A-fragments for first chunk: A[m=j][k=d], lane: j=j0+li
    bf16x8 ka[8];
    if (jc <= itile) {
#pragma unroll
        for (int s = 0; s < 8; ++s) ka[s] = *(const bf16x8*)(kptr + s * 16);
    }

    for (; jc <= itile; jc += 4) {
        // V A-fragments (issued early; latency hides under QK MFMAs)
        bf16x8 va[8];
        va[0] = *(const bf16x8*)(vp0);
        va[1] = *(const bf16x8*)(vp0 + 16);
        va[2] = *(const bf16x8*)(vp1);
        va[3] = *(const bf16x8*)(vp1 + 16);
        va[4] = *(const bf16x8*)(vp2);
        va[5] = *(const bf16x8*)(vp2 + 16);
        va[6] = *(const bf16x8*)(vp3);
        va[7] = *(const bf16x8*)(vp3 + 16);

        // S^T = K' Q'^T : C[m=j][n=i]
        f32x16 sc;
#pragma unroll
        for (int e = 0; e < 16; ++e) sc[e] = 0.f;
        __builtin_amdgcn_s_setprio(1);
#pragma unroll
        for (int s = 0; s < 8; ++s) sc = mfma32(ka[s], qf[s], sc);
        __builtin_amdgcn_s_setprio(0);

        // prefetch next K chunk (overlaps softmax + PV)
        kptr += (size_t)128 * DH;
        if (jc + 4 <= itile) {
#pragma unroll
            for (int s = 0; s < 8; ++s) ka[s] = *(const bf16x8*)(kptr + s * 16);
        }

        // scale (+ diagonal causal mask: j > i)
        f32x16 sv;
#pragma unroll
        for (int e = 0; e < 16; ++e) sv[e] = sc[e] * C;
        if (jc == itile) {
#pragma unroll
            for (int r = 0; r < 16; ++r) {
                const int jrow = (r & 3) + 8 * (r >> 2) + 4 * hi;
                if (jrow > li) sv[r] = -1e30f;
            }
        }

        // row max: in-lane tree + cross-half permlane (no DS)
        float pm = sv[0];
#pragma unroll
        for (int r = 1; r < 16; ++r) pm = fmaxf(pm, sv[r]);
        pm = fmaxf(pm, swap_partner(pm));

        // T13 defer-rescale (log2 domain, THR=8)
        if (!__all(pm <= m + 8.f)) {
            const float mn = fmaxf(m, pm);
            const float f = exp2f(m - mn);
            m = mn;
            l *= f;
#pragma unroll
            for (int c = 0; c < 4; ++c)
#pragma unroll
                for (int e = 0; e < 16; ++e) oacc[c][e] *= f;
        }

        // P = 2^(sv - m), pack to bf16 pairs along j
        float ls = 0.f;
        unsigned Wp[8];
#pragma unroll
        for (int q = 0; q < 4; ++q) {
            const float p0 = exp2f(sv[4 * q + 0] - m);
            const float p1 = exp2f(sv[4 * q + 1] - m);
            const float p2 = exp2f(sv[4 * q + 2] - m);
            const float p3 = exp2f(sv[4 * q + 3] - m);
            ls += (p0 + p1) + (p2 + p3);
            Wp[2 * q] = pk2(p0, p1);
            Wp[2 * q + 1] = pk2(p2, p3);
        }
        l += ls;

        // redistribute P into B-fragments: 4 permlane32_swap (pure VALU)
        plswap(Wp[0], Wp[2]);
        plswap(Wp[1], Wp[3]);
        plswap(Wp[4], Wp[6]);
        plswap(Wp[5], Wp[7]);
        union { unsigned u[4]; bf16x8 v; } pb0, pb1;
        pb0.u[0] = Wp[0]; pb0.u[1] = Wp[1]; pb0.u[2] = Wp[2]; pb0.u[3] = Wp[3];
        pb1.u[0] = Wp[4]; pb1.u[1] = Wp[5]; pb1.u[2] = Wp[6]; pb1.u[3] = Wp[7];

        // PV: O^T[d][i] += V^T[d][j] P[j][i]
        __builtin_amdgcn_s_setprio(1);
        oacc[0] = mfma32(va[0], pb0.v, oacc[0]);
        oacc[0] = mfma32(va[1], pb1.v, oacc[0]);
        oacc[1] = mfma32(va[2], pb0.v, oacc[1]);
        oacc[1] = mfma32(va[3], pb1.v, oacc[1]);
        oacc[2] = mfma32(va[4], pb0.v, oacc[2]);
        oacc[2] = mfma32(va[5], pb1.v, oacc[2]);
        oacc[3] = mfma32(va[6], pb0.v, oacc[3]);
        oacc[3] = mfma32(va[7], pb1.v, oacc[3]);
        __builtin_amdgcn_s_setprio(0);

        vp0 += 128; vp1 += 128; vp2 += 128; vp3 += 128;
    }

    float L = l + swap_partner(l);   // row-total denominator (per chunk subset)

    // ---- 4-way partial merge: (1) w1->A, w3->B; (2) w0+=A, w2+=B;
    //      (3) w2->A; (4) w0+=A, normalize, store.
    if (jseg == 1 || jseg == 3) {
        float (*buf)[32] = (jseg == 1) ? oLa : oLb;
        const int bi = (jseg == 1) ? 0 : 1;
        if (lane < 32) { mlL[bi][0][li] = m; mlL[bi][1][li] = L; }
#pragma unroll
        for (int c = 0; c < 4; ++c)
#pragma unroll
            for (int r = 0; r < 16; ++r) {
                const int d = c * 32 + (r & 3) + 8 * (r >> 2) + 4 * hi;
                buf[d][li] = oacc[c][r];
            }
    }
    __syncthreads();
    if (jseg == 0 || jseg == 2) {
        float (*buf)[32] = (jseg == 0) ? oLa : oLb;
        const int bi = (jseg == 0) ? 0 : 1;
        const float m1 = mlL[bi][0][li], l1 = mlL[bi][1][li];
        const float mx = fmaxf(m, m1);
        const float fa = exp2f(m - mx), fb = exp2f(m1 - mx);
        L = L * fa + l1 * fb;
        m = mx;
#pragma unroll
        for (int c = 0; c < 4; ++c)
#pragma unroll
            for (int r = 0; r < 16; ++r) {
                const int d = c * 32 + (r & 3) + 8 * (r >> 2) + 4 * hi;
                oacc[c][r] = oacc[c][r] * fa + buf[d][li] * fb;
            }
    }
    __syncthreads();
    if (jseg == 2) {
        if (lane < 32) { mlL[0][0][li] = m; mlL[0][1][li] = L; }
#pragma unroll
        for (int c = 0; c < 4; ++c)
#pragma unroll
            for (int r = 0; r < 16; ++r) {
                const int d = c * 32 + (r & 3) + 8 * (r >> 2) + 4 * hi;
                oLa[d][li] = oacc[c][r];
            }
    }
    __syncthreads();
    if (jseg == 0) {
        const float m1 = mlL[0][0][li], l1 = mlL[0][1][li];
        const float mx = fmaxf(m, m1);
        const float fa = exp2f(m - mx), fb = exp2f(m1 - mx);
        const float inv = 1.f / (L * fa + l1 * fb);
        bf16_t* orow = obuf + ((size_t)b * T_SEQ + i0 + li) * HKDIM + h * DH;
#pragma unroll
        for (int c = 0; c < 4; ++c)
#pragma unroll
            for (int q = 0; q < 4; ++q) {
                bf16x4_t o4;
#pragma unroll
                for (int rr = 0; rr < 4; ++rr) {
                    const int d = c * 32 + q * 8 + 4 * hi + rr;
                    o4[rr] = (bf16_t)((oacc[c][4 * q + rr] * fa + oLa[d][li] * fb) * inv);
                }
                *(bf16x4_t*)(orow + c * 32 + q * 8 + 4 * hi) = o4;
            }
    }
}

// ---------------------------------------------------------------------------
// Kernel 4: output projection, split-K over waves.
//   out[t][b][n] = sum_c ob[b][t][c]*Wo[n][c]+bo[n].  16 rows/block;
//   wave w covers kc in [8w, 8w+8); 8 col-groups x 8 indep MFMA chains;
//   32KB LDS reduction, wave w stores col-groups 2w, 2w+1.
// ---------------------------------------------------------------------------
__global__ __launch_bounds__(256) void outproj_kernel(
        const bf16_t* __restrict__ obuf, const bf16_t* __restrict__ wo,
        const float* __restrict__ bo, float* __restrict__ out) {
    const int lane = threadIdx.x & 63, wave = threadIdx.x >> 6;
    const int lr = lane & 15, lq = lane >> 4;
    const int rm0 = blockIdx.x * 16;
    __shared__ float red[4][8][256];   // [wave][g][lane*4]

    f32x4 acc[8];
#pragma unroll
    for (int g = 0; g < 8; ++g) acc[g] = {0.f, 0.f, 0.f, 0.f};
#pragma unroll 2
    for (int k8 = 0; k8 < 8; ++k8) {
        const int kc = wave * 8 + k8;
        bf16x8 aF = *(const bf16x8*)(obuf + (size_t)(rm0 + lr) * HKDIM + kc * 32 + lq * 8);
#pragma unroll
        for (int g = 0; g < 8; ++g) {
            bf16x8 bF = *(const bf16x8*)(wo + (size_t)(g * 16 + lr) * HKDIM + kc * 32 + lq * 8);
            acc[g] = mfma16(aF, bF, acc[g]);
        }
    }
#pragma unroll
    for (int g = 0; g < 8; ++g)
        *(f32x4*)&red[wave][g][lane * 4] = acc[g];
    __syncthreads();
#pragma unroll
    for (int gi = 0; gi < 2; ++gi) {
        const int g = wave * 2 + gi;
        f32x4 s = *(const f32x4*)&red[0][g][lane * 4];
#pragma unroll
        for (int w = 1; w < 4; ++w) {
            f32x4 t = *(const f32x4*)&red[w][g][lane * 4];
            s[0] += t[0]; s[1] += t[1]; s[2] += t[2]; s[3] += t[3];
        }
        const int col = g * 16 + lr;
        const float bias = bo[col];
#pragma unroll
        for (int r = 0; r < 4; ++r) {
            const int row = rm0 + lq * 4 + r;
            const int bb = row >> 10, tt = row & 1023;
            out[((size_t)tt * BATCH + bb) * DH + col] = s[r] + bias;
        }
    }
}

// ---------------------------------------------------------------------------
extern "C" void kernel_launch(void* const* d_in, const int* in_sizes, int n_in,
                              void* d_out, int out_size, void* d_ws, size_t ws_size,
                              hipStream_t stream) {
    const float* x  = (const float*)d_in[0];
    const float* Wk = (const float*)d_in[1];
    const float* bk = (const float*)d_in[2];
    const float* Wq = (const float*)d_in[3];
    const float* bq = (const float*)d_in[4];
    const float* Wv = (const float*)d_in[5];
    const float* bv = (const float*)d_in[6];
    const float* Wo = (const float*)d_in[7];
    const float* bo = (const float*)d_in[8];
    float* out = (float*)d_out;

    char* ws = (char*)d_ws;
    size_t off = 0;
    bf16_t* xb  = (bf16_t*)(ws + off); off += (size_t)BATCH * T_SEQ * DH * 2;       // 2 MiB
    bf16_t* w3  = (bf16_t*)(ws + off); off += (size_t)3 * HKDIM * DH * 2;           // 0.75 MiB
    bf16_t* wo  = (bf16_t*)(ws + off); off += (size_t)DH * HKDIM * 2;               // 0.25 MiB
    bf16_t* kb  = (bf16_t*)(ws + off); off += (size_t)BATCH * NH * T_SEQ * DH * 2;  // 16 MiB
    bf16_t* qb  = (bf16_t*)(ws + off); off += (size_t)BATCH * NH * T_SEQ * DH * 2;  // 16 MiB
    bf16_t* vtb = (bf16_t*)(ws + off); off += (size_t)BATCH * NH * T_SEQ * DH * 2;  // 16 MiB
    bf16_t* ob  = (bf16_t*)(ws + off); off += (size_t)BATCH * T_SEQ * HKDIM * 2;    // 16 MiB

    convert_kernel<<<1536, 256, 0, stream>>>(x, Wk, Wq, Wv, Wo, xb, w3, wo);
    proj_kernel<<<dim3(128, 48), 256, 0, stream>>>(xb, w3, bk, bq, bv, kb, qb, vtb);
    attn_kernel<<<2048, 256, 0, stream>>>(kb, qb, vtb, ob);
    outproj_kernel<<<512, 256, 0, stream>>>(ob, wo, bo, out);
}

// Round 6
// 161.918 us; speedup vs baseline: 1.1786x; 1.1786x over previous
//
#include <hip/hip_runtime.h>
#include <hip/hip_bf16.h>

typedef __bf16 bf16_t;
typedef __bf16 bf16x2_t __attribute__((ext_vector_type(2)));
typedef __bf16 bf16x4_t __attribute__((ext_vector_type(4)));
typedef __bf16 bf16x8 __attribute__((ext_vector_type(8)));
typedef float f32x4 __attribute__((ext_vector_type(4)));
typedef float f32x16 __attribute__((ext_vector_type(16)));
typedef unsigned int u32x2 __attribute__((ext_vector_type(2)));

#define T_SEQ 1024
#define BATCH 8
#define NH 8
#define DH 128
#define HKDIM 1024  // NH*DH

static __device__ __forceinline__ f32x4 mfma16(bf16x8 a, bf16x8 b, f32x4 c) {
    return __builtin_amdgcn_mfma_f32_16x16x32_bf16(a, b, c, 0, 0, 0);
}
static __device__ __forceinline__ f32x16 mfma32(bf16x8 a, bf16x8 b, f32x16 c) {
    return __builtin_amdgcn_mfma_f32_32x32x16_bf16(a, b, c, 0, 0, 0);
}

static __device__ __forceinline__ unsigned pk2(float a, float b) {
    bf16x2_t t;
    t[0] = (bf16_t)a;
    t[1] = (bf16_t)b;
    union { bf16x2_t v; unsigned u; } c;
    c.v = t;
    return c.u;
}

// v_permlane32_swap via builtin: r[0] = {a.lo, b.lo}, r[1] = {a.hi, b.hi}
static __device__ __forceinline__ void plswap(unsigned& a, unsigned& b) {
    u32x2 r = __builtin_amdgcn_permlane32_swap(a, b, false, false);
    a = r[0];
    b = r[1];
}

// value of x from lane^32 (pure VALU, no DS)
static __device__ __forceinline__ float swap_partner(float x) {
    u32x2 r = __builtin_amdgcn_permlane32_swap(__float_as_uint(x),
                                               __float_as_uint(x), false, false);
    return __uint_as_float((threadIdx.x & 32) ? r[0] : r[1]);
}

// ---------------------------------------------------------------------------
// Kernel 1: convert inputs to bf16 working layouts (float4-vectorized).
// ---------------------------------------------------------------------------
__global__ __launch_bounds__(256) void convert_kernel(
        const float* __restrict__ x,
        const float* __restrict__ Wk, const float* __restrict__ Wq,
        const float* __restrict__ Wv, const float* __restrict__ Wo,
        bf16_t* __restrict__ xb, bf16_t* __restrict__ w3,
        bf16_t* __restrict__ wo) {
    const int n1 = T_SEQ * BATCH * DH;        // 1048576
    const int n2 = n1 + 3 * HKDIM * DH;       // +393216
    const int n3 = n2 + DH * HKDIM;           // +131072
    const int i = (blockIdx.x * 256 + threadIdx.x) * 4;
    if (i >= n3) return;
    const float* src;
    bf16_t* dst;
    if (i < n1) {
        int d = i & 127, t = (i >> 7) & 1023, b = i >> 17;
        src = x + (t * BATCH + b) * DH + d;
        dst = xb + i;
    } else if (i < n2) {
        int j = i - n1;
        int p = j >> 17;
        const float* W = (p == 0) ? Wk : (p == 1 ? Wq : Wv);
        src = W + (j & 131071);
        dst = w3 + j;
    } else {
        int j = i - n2;
        src = Wo + j;
        dst = wo + j;
    }
    f32x4 v = *(const f32x4*)src;
    bf16x4_t o;
    o[0] = (bf16_t)v[0]; o[1] = (bf16_t)v[1];
    o[2] = (bf16_t)v[2]; o[3] = (bf16_t)v[3];
    *(bf16x4_t*)dst = o;
}

// ---------------------------------------------------------------------------
// Kernel 2: QKV projection. K/Q written [bh][t][d]. V written TRANSPOSED
//   [bh][d][t] via an LDS-staged 64x64 tile so global stores are contiguous
//   128B d-rows (fixes the 8B/2KB-stride scatter of earlier rounds).
// ---------------------------------------------------------------------------
__global__ __launch_bounds__(256) void proj_kernel(
        const bf16_t* __restrict__ xb, const bf16_t* __restrict__ w3,
        const float* __restrict__ bk, const float* __restrict__ bq,
        const float* __restrict__ bv,
        bf16_t* __restrict__ kbuf, bf16_t* __restrict__ qbuf,
        bf16_t* __restrict__ vtbuf) {
    const int lane = threadIdx.x & 63;
    const int wave = threadIdx.x >> 6;
    const int lr = lane & 15, lq = lane >> 4;
    const int rm0 = blockIdx.x * 64 + wave * 16;
    const int cb0 = blockIdx.y * 64;
    const bool isV = (blockIdx.y >= 32);

    __shared__ bf16_t vL[64][72];   // [col_local(d)][row_local(t)], 16B-aligned rows

    bf16x8 aF[4];
#pragma unroll
    for (int kc = 0; kc < 4; ++kc)
        aF[kc] = *(const bf16x8*)(xb + (rm0 + lr) * DH + kc * 32 + lq * 8);

#pragma unroll
    for (int nc = 0; nc < 4; ++nc) {
        const int col0 = cb0 + nc * 16;
        f32x4 acc = {0.f, 0.f, 0.f, 0.f};
#pragma unroll
        for (int kc = 0; kc < 4; ++kc) {
            bf16x8 bF = *(const bf16x8*)(w3 + (col0 + lr) * DH + kc * 32 + lq * 8);
            acc = mfma16(aF[kc], bF, acc);
        }
        const int col = col0 + lr;
        const int p = col >> 10, within = col & 1023;
        const int h = within >> 7, d = within & 127;
        const float bias = (p == 0) ? bk[within] : (p == 1 ? bq[within] : bv[within]);
        if (isV) {
            // stage V tile in LDS, transposed: vL[d_local][t_local]
#pragma unroll
            for (int r = 0; r < 4; ++r)
                vL[nc * 16 + lr][wave * 16 + lq * 4 + r] = (bf16_t)(acc[r] + bias);
        } else {
            bf16_t* dst = (p == 0) ? kbuf : qbuf;
#pragma unroll
            for (int r = 0; r < 4; ++r) {
                const int row = rm0 + lq * 4 + r;
                const int bb = row >> 10, tt = row & 1023;
                dst[((size_t)(bb * NH + h) * T_SEQ + tt) * DH + d] =
                    (bf16_t)(acc[r] + bias);
            }
        }
    }

    if (isV) {
        __syncthreads();
        const int tid = threadIdx.x;
        const int dl = tid >> 2;           // 0..63
        const int ts = (tid & 3) * 16;     // 0,16,32,48
        const int by = blockIdx.y - 32;
        const int h = by >> 1;
        const int d = (by & 1) * 64 + dl;
        const int bb = blockIdx.x >> 4;
        const int t0 = (blockIdx.x & 15) * 64;
        bf16x8 o0 = *(const bf16x8*)&vL[dl][ts];
        bf16x8 o1 = *(const bf16x8*)&vL[dl][ts + 8];
        bf16_t* dst = vtbuf + ((size_t)(bb * NH + h) * DH + d) * T_SEQ + t0 + ts;
        *(bf16x8*)dst = o0;
        *(bf16x8*)(dst + 8) = o1;
    }
}

// ---------------------------------------------------------------------------
// Kernel 3: flash attention (r4 structure + T5 setprio).
//   Roles: Q' := K_proj (rows i), K' := Q_proj (cols j), V := V_proj.
//   S^T = mfma32(K'[j], Q'[i]); 2 waves = 2 j-segments of one 32-row i-tile,
//   merged via LDS at the end. Zero DS ops / barriers in the main loop.
//   Grid: 2048 x 128thr; bx>>6 = reversed itile (heavy first), bx&63 = bh.
// ---------------------------------------------------------------------------
__global__ __launch_bounds__(128, 2) void attn_kernel(
        const bf16_t* __restrict__ kbuf, const bf16_t* __restrict__ qbuf,
        const bf16_t* __restrict__ vtb, bf16_t* __restrict__ obuf) {
    const int bx = blockIdx.x;
    const int itile = 31 - (bx >> 6);
    const int bh = bx & 63;
    const int b = bh >> 3, h = bh & 7;
    const int jseg = threadIdx.x >> 6;
    const int lane = threadIdx.x & 63;
    const int li = lane & 31;
    const int hi = lane >> 5;
    const int i0 = itile * 32;

    const bf16_t* Qp = kbuf + (size_t)bh * T_SEQ * DH;  // rows i (key positions)
    const bf16_t* Kp = qbuf + (size_t)bh * T_SEQ * DH;  // cols j (query positions)
    const bf16_t* Vt = vtb + (size_t)bh * DH * T_SEQ;   // [d][t]

    __shared__ float oL[128][32];   // [d][i] partial from jseg=1 (conflict-free)
    __shared__ float mlL[2][32];

    // persistent Q B-fragments: B[k=d][n=i], lane: i=li, k = s*16 + hi*8 + e
    bf16x8 qf[8];
#pragma unroll
    for (int s = 0; s < 8; ++s)
        qf[s] = *(const bf16x8*)(Qp + (size_t)(i0 + li) * DH + s * 16 + hi * 8);

    f32x16 oacc[4];
#pragma unroll
    for (int c = 0; c < 4; ++c)
#pragma unroll
        for (int e = 0; e < 16; ++e) oacc[c][e] = 0.f;

    float m = 0.f, l = 0.f;
    const float C = 0.08838834764831845f * 1.4426950408889634f;  // scale*log2e

    int jc = jseg;
    const bf16_t* kptr = Kp + (size_t)(jc * 32 + li) * DH + hi * 8;
    const bf16_t* vp0 = Vt + (size_t)li * T_SEQ + jc * 32 + hi * 8;
    const bf16_t* vp1 = vp0 + (size_t)32 * T_SEQ;
    const bf16_t* vp2 = vp0 + (size_t)64 * T_SEQ;
    const bf16_t* vp3 = vp0 + (size_t)96 * T_SEQ;

    // K A-fragments for first chunk: A[m=j][k=d], lane: j=j0+li
    bf16x8 ka[8];
    if (jc <= itile) {
#pragma unroll
        for (int s = 0; s < 8; ++s) ka[s] = *(const bf16x8*)(kptr + s * 16);
    }

    for (; jc <= itile; jc += 2) {
        // V A-fragments (issued early; latency hides under QK MFMAs)
        bf16x8 va[8];
        va[0] = *(const bf16x8*)(vp0);
        va[1] = *(const bf16x8*)(vp0 + 16);
        va[2] = *(const bf16x8*)(vp1);
        va[3] = *(const bf16x8*)(vp1 + 16);
        va[4] = *(const bf16x8*)(vp2);
        va[5] = *(const bf16x8*)(vp2 + 16);
        va[6] = *(const bf16x8*)(vp3);
        va[7] = *(const bf16x8*)(vp3 + 16);

        // S^T = K' Q'^T : C[m=j][n=i]
        f32x16 sc;
#pragma unroll
        for (int e = 0; e < 16; ++e) sc[e] = 0.f;
        __builtin_amdgcn_s_setprio(1);
#pragma unroll
        for (int s = 0; s < 8; ++s) sc = mfma32(ka[s], qf[s], sc);
        __builtin_amdgcn_s_setprio(0);

        // prefetch next K chunk (overlaps softmax + PV)
        kptr += (size_t)64 * DH;
        if (jc + 2 <= itile) {
#pragma unroll
            for (int s = 0; s < 8; ++s) ka[s] = *(const bf16x8*)(kptr + s * 16);
        }

        // scale (+ diagonal causal mask: j > i)
        f32x16 sv;
#pragma unroll
        for (int e = 0; e < 16; ++e) sv[e] = sc[e] * C;
        if (jc == itile) {
#pragma unroll
            for (int r = 0; r < 16; ++r) {
                const int jrow = (r & 3) + 8 * (r >> 2) + 4 * hi;
                if (jrow > li) sv[r] = -1e30f;
            }
        }

        // row max: in-lane tree + cross-half permlane (no DS)
        float pm = sv[0];
#pragma unroll
        for (int r = 1; r < 16; ++r) pm = fmaxf(pm, sv[r]);
        pm = fmaxf(pm, swap_partner(pm));

        // T13 defer-rescale (log2 domain, THR=8)
        if (!__all(pm <= m + 8.f)) {
            const float mn = fmaxf(m, pm);
            const float f = exp2f(m - mn);
            m = mn;
            l *= f;
#pragma unroll
            for (int c = 0; c < 4; ++c)
#pragma unroll
                for (int e = 0; e < 16; ++e) oacc[c][e] *= f;
        }

        // P = 2^(sv - m), pack to bf16 pairs along j
        float ls = 0.f;
        unsigned Wp[8];
#pragma unroll
        for (int q = 0; q < 4; ++q) {
            const float p0 = exp2f(sv[4 * q + 0] - m);
            const float p1 = exp2f(sv[4 * q + 1] - m);
            const float p2 = exp2f(sv[4 * q + 2] - m);
            const float p3 = exp2f(sv[4 * q + 3] - m);
            ls += (p0 + p1) + (p2 + p3);
            Wp[2 * q] = pk2(p0, p1);
            Wp[2 * q + 1] = pk2(p2, p3);
        }
        l += ls;

        // redistribute P into B-fragments: 4 permlane32_swap (pure VALU)
        plswap(Wp[0], Wp[2]);
        plswap(Wp[1], Wp[3]);
        plswap(Wp[4], Wp[6]);
        plswap(Wp[5], Wp[7]);
        union { unsigned u[4]; bf16x8 v; } pb0, pb1;
        pb0.u[0] = Wp[0]; pb0.u[1] = Wp[1]; pb0.u[2] = Wp[2]; pb0.u[3] = Wp[3];
        pb1.u[0] = Wp[4]; pb1.u[1] = Wp[5]; pb1.u[2] = Wp[6]; pb1.u[3] = Wp[7];

        // PV: O^T[d][i] += V^T[d][j] P[j][i]
        __builtin_amdgcn_s_setprio(1);
        oacc[0] = mfma32(va[0], pb0.v, oacc[0]);
        oacc[0] = mfma32(va[1], pb1.v, oacc[0]);
        oacc[1] = mfma32(va[2], pb0.v, oacc[1]);
        oacc[1] = mfma32(va[3], pb1.v, oacc[1]);
        oacc[2] = mfma32(va[4], pb0.v, oacc[2]);
        oacc[2] = mfma32(va[5], pb1.v, oacc[2]);
        oacc[3] = mfma32(va[6], pb0.v, oacc[3]);
        oacc[3] = mfma32(va[7], pb1.v, oacc[3]);
        __builtin_amdgcn_s_setprio(0);

        vp0 += 64; vp1 += 64; vp2 += 64; vp3 += 64;
    }

    const float lfull = l + swap_partner(l);

    // merge the two j-segments via LDS
    if (jseg == 1) {
        if (lane < 32) { mlL[0][li] = m; mlL[1][li] = lfull; }
#pragma unroll
        for (int c = 0; c < 4; ++c)
#pragma unroll
            for (int r = 0; r < 16; ++r) {
                const int d = c * 32 + (r & 3) + 8 * (r >> 2) + 4 * hi;
                oL[d][li] = oacc[c][r];
            }
    }
    __syncthreads();
    if (jseg == 0) {
        const float m1 = mlL[0][li], l1 = mlL[1][li];
        const float mx = fmaxf(m, m1);
        const float fa = exp2f(m - mx), fb = exp2f(m1 - mx);
        const float inv = 1.f / (lfull * fa + l1 * fb);
        bf16_t* orow = obuf + ((size_t)b * T_SEQ + i0 + li) * HKDIM + h * DH;
#pragma unroll
        for (int c = 0; c < 4; ++c)
#pragma unroll
            for (int q = 0; q < 4; ++q) {
                bf16x4_t o4;
#pragma unroll
                for (int rr = 0; rr < 4; ++rr) {
                    const int d = c * 32 + q * 8 + 4 * hi + rr;
                    o4[rr] = (bf16_t)((oacc[c][4 * q + rr] * fa + oL[d][li] * fb) * inv);
                }
                *(bf16x4_t*)(orow + c * 32 + q * 8 + 4 * hi) = o4;
            }
    }
}

// ---------------------------------------------------------------------------
// Kernel 4: output projection, split-K over waves.
//   out[t][b][n] = sum_c ob[b][t][c]*Wo[n][c]+bo[n].  16 rows/block;
//   wave w covers kc in [8w, 8w+8); 8 col-groups x 8 indep MFMA chains;
//   32KB LDS reduction, wave w stores col-groups 2w, 2w+1.
// ---------------------------------------------------------------------------
__global__ __launch_bounds__(256) void outproj_kernel(
        const bf16_t* __restrict__ obuf, const bf16_t* __restrict__ wo,
        const float* __restrict__ bo, float* __restrict__ out) {
    const int lane = threadIdx.x & 63, wave = threadIdx.x >> 6;
    const int lr = lane & 15, lq = lane >> 4;
    const int rm0 = blockIdx.x * 16;
    __shared__ float red[4][8][256];   // [wave][g][lane*4]

    f32x4 acc[8];
#pragma unroll
    for (int g = 0; g < 8; ++g) acc[g] = {0.f, 0.f, 0.f, 0.f};
#pragma unroll 2
    for (int k8 = 0; k8 < 8; ++k8) {
        const int kc = wave * 8 + k8;
        bf16x8 aF = *(const bf16x8*)(obuf + (size_t)(rm0 + lr) * HKDIM + kc * 32 + lq * 8);
#pragma unroll
        for (int g = 0; g < 8; ++g) {
            bf16x8 bF = *(const bf16x8*)(wo + (size_t)(g * 16 + lr) * HKDIM + kc * 32 + lq * 8);
            acc[g] = mfma16(aF, bF, acc[g]);
        }
    }
#pragma unroll
    for (int g = 0; g < 8; ++g)
        *(f32x4*)&red[wave][g][lane * 4] = acc[g];
    __syncthreads();
#pragma unroll
    for (int gi = 0; gi < 2; ++gi) {
        const int g = wave * 2 + gi;
        f32x4 s = *(const f32x4*)&red[0][g][lane * 4];
#pragma unroll
        for (int w = 1; w < 4; ++w) {
            f32x4 t = *(const f32x4*)&red[w][g][lane * 4];
            s[0] += t[0]; s[1] += t[1]; s[2] += t[2]; s[3] += t[3];
        }
        const int col = g * 16 + lr;
        const float bias = bo[col];
#pragma unroll
        for (int r = 0; r < 4; ++r) {
            const int row = rm0 + lq * 4 + r;
            const int bb = row >> 10, tt = row & 1023;
            out[((size_t)tt * BATCH + bb) * DH + col] = s[r] + bias;
        }
    }
}

// ---------------------------------------------------------------------------
extern "C" void kernel_launch(void* const* d_in, const int* in_sizes, int n_in,
                              void* d_out, int out_size, void* d_ws, size_t ws_size,
                              hipStream_t stream) {
    const float* x  = (const float*)d_in[0];
    const float* Wk = (const float*)d_in[1];
    const float* bk = (const float*)d_in[2];
    const float* Wq = (const float*)d_in[3];
    const float* bq = (const float*)d_in[4];
    const float* Wv = (const float*)d_in[5];
    const float* bv = (const float*)d_in[6];
    const float* Wo = (const float*)d_in[7];
    const float* bo = (const float*)d_in[8];
    float* out = (float*)d_out;

    char* ws = (char*)d_ws;
    size_t off = 0;
    bf16_t* xb  = (bf16_t*)(ws + off); off += (size_t)BATCH * T_SEQ * DH * 2;       // 2 MiB
    bf16_t* w3  = (bf16_t*)(ws + off); off += (size_t)3 * HKDIM * DH * 2;           // 0.75 MiB
    bf16_t* wo  = (bf16_t*)(ws + off); off += (size_t)DH * HKDIM * 2;               // 0.25 MiB
    bf16_t* kb  = (bf16_t*)(ws + off); off += (size_t)BATCH * NH * T_SEQ * DH * 2;  // 16 MiB
    bf16_t* qb  = (bf16_t*)(ws + off); off += (size_t)BATCH * NH * T_SEQ * DH * 2;  // 16 MiB
    bf16_t* vtb = (bf16_t*)(ws + off); off += (size_t)BATCH * NH * T_SEQ * DH * 2;  // 16 MiB
    bf16_t* ob  = (bf16_t*)(ws + off); off += (size_t)BATCH * T_SEQ * HKDIM * 2;    // 16 MiB

    convert_kernel<<<1536, 256, 0, stream>>>(x, Wk, Wq, Wv, Wo, xb, w3, wo);
    proj_kernel<<<dim3(128, 48), 256, 0, stream>>>(xb, w3, bk, bq, bv, kb, qb, vtb);
    attn_kernel<<<2048, 128, 0, stream>>>(kb, qb, vtb, ob);
    outproj_kernel<<<512, 256, 0, stream>>>(ob, wo, bo, out);
}